// Round 14
// baseline (561.519 us; speedup 1.0000x reference)
//
#include <hip/hip_runtime.h>

#define DD 128
#define K2 256     // concatenated K: [msg | ego*msg]
#define NBMAX 1024 // max bucket count (N/128)
#define COLMASK 0x01FFFFFF
#define SCAP 4096  // sortbkt LDS out-buffer capacity (entries)

typedef short short8 __attribute__((ext_vector_type(8)));
typedef float f32x4  __attribute__((ext_vector_type(4)));

static inline size_t align256(size_t x){ return (x + 255) & ~(size_t)255; }

__device__ __forceinline__ unsigned short f2bf(float x){
  unsigned int u = __builtin_bit_cast(unsigned int, x);
  u += 0x7fff + ((u >> 16) & 1);          // RNE fp32 -> bf16
  return (unsigned short)(u >> 16);
}
__device__ __forceinline__ float bf2f(unsigned short h){
  unsigned int u = ((unsigned int)h) << 16;
  return __builtin_bit_cast(float, u);
}

__device__ __forceinline__ short8 prod8(short8 mv, short8 ev){
  short8 r;
#pragma unroll
  for (int u = 0; u < 8; u++){
    float p = bf2f((unsigned short)mv[u]) * bf2f((unsigned short)ev[u]);
    r[u] = (short)f2bf(p);
  }
  return r;
}

// ---------------- bucket histogram: LDS hist -> few global atomics ----------------
__global__ __launch_bounds__(256) void bucket_hist_kernel(
    const int* __restrict__ ei, int E, int* __restrict__ bcnt, int NB){
  __shared__ int lh[NBMAX];
  int t = threadIdx.x;
  int base = blockIdx.x * 8192;
  for (int j = t; j < NB; j += 256) lh[j] = 0;
  __syncthreads();
#pragma unroll
  for (int i = 0; i < 32; i++){
    int e = base + i*256 + t;
    if (e < E) atomicAdd(&lh[ei[e] >> 7], 1);
  }
  __syncthreads();
  for (int j = t; j < NB; j += 256){
    int c = lh[j];
    if (c) atomicAdd(&bcnt[j], c);
  }
}

// ---------------- bucket scan: bbase = excl scan(bcnt); bcur = bbase ----------------
__global__ __launch_bounds__(1024) void bucket_scan_kernel(
    const int* __restrict__ bcnt, int* __restrict__ bbase, int* __restrict__ bcur, int NB){
  __shared__ int a[NBMAX], btmp[NBMAX];
  int t = threadIdx.x;
  a[t] = (t < NB) ? bcnt[t] : 0;
  __syncthreads();
  int* src = a; int* dst = btmp;
  for (int o = 1; o < 1024; o <<= 1){
    int val = src[t];
    if (t >= o) val += src[t - o];
    dst[t] = val;
    __syncthreads();
    int* tm = src; src = dst; dst = tm;
  }
  int excl = (t == 0) ? 0 : src[t-1];
  if (t < NB){ bbase[t] = excl; bcur[t] = excl; }
}

// ---------------- binned fill, phase A ----------------
__global__ __launch_bounds__(256) void fill_binned_kernel(
    const int* __restrict__ ei, const float* __restrict__ ew, int E,
    int* __restrict__ bcur, int2* __restrict__ csre, int NB){
  __shared__ int lhist[NBMAX];
  __shared__ int lbase[NBMAX];
  int t = threadIdx.x;
  int base = blockIdx.x * 4096;
  for (int j = t; j < NB; j += 256) lhist[j] = 0;
  __syncthreads();
  int rows[16];
#pragma unroll
  for (int i = 0; i < 16; i++){
    int e = base + i*256 + t;
    int r = (e < E) ? ei[e] : -1;
    rows[i] = r;
    if (r >= 0) atomicAdd(&lhist[r >> 7], 1);
  }
  __syncthreads();
  for (int j = t; j < NB; j += 256){
    int c = lhist[j];
    lbase[j] = c ? atomicAdd(&bcur[j], c) : 0;
    lhist[j] = 0;
  }
  __syncthreads();
#pragma unroll
  for (int i = 0; i < 16; i++){
    int e = base + i*256 + t;
    int r = rows[i];
    if (r >= 0){
      int b = r >> 7;
      int pos = lbase[b] + atomicAdd(&lhist[b], 1);
      int col = ei[E + e];
      float w = ew[e];
      csre[pos] = make_int2(((r & 127) << 25) | col, __float_as_int(w));
    }
  }
}

// ---------------- merged phase B: deg hist + local scan + atomic base + rank -> exact CSR --
// One block per 128-row bucket.  Claims its csre2 region via atomicAdd(gcur) (placement
// order irrelevant -- each row's span is stored in rp2[r] = (start, end)).  No padding.
__global__ __launch_bounds__(256) void sortbkt2_kernel(
    const int* __restrict__ bbase, const int* __restrict__ bcur,
    const int2* __restrict__ csre, int2* __restrict__ csre2,
    int2* __restrict__ rp2, int* __restrict__ gcur, int N){
  __shared__ int2 obuf[SCAP];
  __shared__ int lc[128], lcur[128], lrp[128];
  __shared__ int sa[128], sb[128];
  __shared__ int gbase;
  int b = blockIdx.x, t = threadIdx.x;
  int r0 = b*128;
  if (t < 128){ lc[t] = 0; lcur[t] = 0; }
  __syncthreads();
  int beg = bbase[b], bend = bcur[b];
  for (int i = beg + t; i < bend; i += 256)
    atomicAdd(&lc[((unsigned int)csre[i].x) >> 25], 1);
  __syncthreads();
  int d = (t < 128) ? lc[t] : 0;
  if (t < 128) sa[t] = d;
  __syncthreads();
  int* s0 = sa; int* s1 = sb;
  for (int o = 1; o < 128; o <<= 1){
    if (t < 128){
      int v = s0[t];
      if (t >= o) v += s0[t - o];
      s1[t] = v;
    }
    __syncthreads();
    int* tm = s0; s0 = s1; s1 = tm;
  }
  int total = s0[127];          // == bend - beg
  if (t == 0) gbase = atomicAdd(gcur, total);
  __syncthreads();
  int gb = gbase;
  if (t < 128){
    int excl = t ? s0[t-1] : 0;
    lrp[t] = excl;
    int gr = r0 + t;
    if (gr < N) rp2[gr] = make_int2(gb + excl, gb + excl + d);
  }
  __syncthreads();
  if (total <= SCAP){
    for (int i = beg + t; i < bend; i += 256){
      int2 e = csre[i];
      int rl = ((unsigned int)e.x) >> 25;
      int pos = lrp[rl] + atomicAdd(&lcur[rl], 1);
      obuf[pos] = e;
    }
    __syncthreads();
    for (int i = t; i < total; i += 256) csre2[gb + i] = obuf[i];   // coalesced dump
  } else {
    for (int i = beg + t; i < bend; i += 256){
      int2 e = csre[i];
      int rl = ((unsigned int)e.x) >> 25;
      int pos = gb + lrp[rl] + atomicAdd(&lcur[rl], 1);
      csre2[pos] = e;
    }
  }
}

// ---------------- fused: weight pack + emb->bf16 stage0 (interleaved feat4) ----------------
__global__ void pack_cvt_kernel(const float* __restrict__ gcw, const float* __restrict__ biw,
                                unsigned short* __restrict__ wb, int LYR,
                                const float* __restrict__ emb, unsigned int* __restrict__ feat4u,
                                int n2, int fsU){
  int i = blockIdx.x*blockDim.x + threadIdx.x;
  int wtotal = LYR*DD*K2;
  if (i < wtotal){
    int l = i / (DD*K2);
    int r = i - l*(DD*K2);
    int n = r >> 8;
    int k = r & (K2-1);
    float v = (k < DD) ? gcw[(size_t)l*DD*DD + n*DD + k]
                       : biw[(size_t)l*DD*DD + n*DD + (k - DD)];
    wb[i] = f2bf(v);
    return;
  }
  int j = i - wtotal;
  if (j < n2){
    float2 v = *(const float2*)(emb + (size_t)j*2);
    int n = j >> 6, c = j & 63;
    feat4u[(size_t)n*fsU + c] = (unsigned int)f2bf(v.x) | ((unsigned int)f2bf(v.y) << 16);
  }
}

// ---------------- gather (exact CSR): 16/8 batches + masked remainder batch ----------------
__global__ void gather_kernel(const int2* __restrict__ rp2, const int2* __restrict__ csre,
                              const unsigned short* __restrict__ feat, int fs,
                              unsigned int* __restrict__ msgh, int N){
  int wid = (int)(((size_t)blockIdx.x*blockDim.x + threadIdx.x) >> 6);
  int lane = threadIdx.x & 63;
  if (wid >= N) return;
  int2 rp = rp2[wid];
  int beg = rp.x, end = rp.y;
  float ax = 0.f, ay = 0.f;
  int k = beg;
  for (; k + 16 <= end; k += 16){     // 16 independent row-gathers in flight
    int2 e[16]; unsigned int v[16];
#pragma unroll
    for (int u = 0; u < 16; u++) e[u] = csre[k+u];
#pragma unroll
    for (int u = 0; u < 16; u++)
      v[u] = *(const unsigned int*)(feat + (size_t)(e[u].x & COLMASK)*fs + lane*2);
#pragma unroll
    for (int u = 0; u < 16; u++){
      float w = __int_as_float(e[u].y);
      ax = fmaf(w, bf2f((unsigned short)v[u]), ax);
      ay = fmaf(w, bf2f((unsigned short)(v[u]>>16)), ay);
    }
  }
  for (; k + 8 <= end; k += 8){
    int2 e[8]; unsigned int v[8];
#pragma unroll
    for (int u = 0; u < 8; u++) e[u] = csre[k+u];
#pragma unroll
    for (int u = 0; u < 8; u++)
      v[u] = *(const unsigned int*)(feat + (size_t)(e[u].x & COLMASK)*fs + lane*2);
#pragma unroll
    for (int u = 0; u < 8; u++){
      float w = __int_as_float(e[u].y);
      ax = fmaf(w, bf2f((unsigned short)v[u]), ax);
      ay = fmaf(w, bf2f((unsigned short)(v[u]>>16)), ay);
    }
  }
  if (k < end){                       // masked batch: dead slots clamp to last edge, w=0
    int last = end - 1;
    int2 e[8]; unsigned int v[8];
#pragma unroll
    for (int u = 0; u < 8; u++){
      int idx = k + u;
      bool ok = idx < end;
      int2 ee = csre[ok ? idx : last];
      if (!ok) ee.y = 0;              // duplicate load (L1-hot line), zero weight
      e[u] = ee;
    }
#pragma unroll
    for (int u = 0; u < 8; u++)
      v[u] = *(const unsigned int*)(feat + (size_t)(e[u].x & COLMASK)*fs + lane*2);
#pragma unroll
    for (int u = 0; u < 8; u++){
      float w = __int_as_float(e[u].y);
      ax = fmaf(w, bf2f((unsigned short)v[u]), ax);
      ay = fmaf(w, bf2f((unsigned short)(v[u]>>16)), ay);
    }
  }
  msgh[(size_t)wid*(DD/2) + lane] = (unsigned int)f2bf(ax) | ((unsigned int)f2bf(ay) << 16);
}

// ---------------- transform (bf16 MFMA, K=256), LDS-free, strided feature rows ----------
__global__ __launch_bounds__(256) void transform_mfma_kernel(
    const unsigned short* __restrict__ ego_in, const unsigned short* __restrict__ msgh,
    int fs, const unsigned short* __restrict__ wb, const float* __restrict__ gcb,
    const float* __restrict__ bib, unsigned short* __restrict__ ego_out,
    float* __restrict__ nscale, int N){   // nscale: stride-3 base for this layer
  int t = threadIdx.x;
  int wave = t >> 6, lane = t & 63;
  int m = lane & 15, q = lane >> 4;
  int wr0 = blockIdx.x * 128 + wave * 32;

  float bias[8];
#pragma unroll
  for (int ct = 0; ct < 8; ct++) bias[ct] = gcb[ct*16 + m] + bib[ct*16 + m];

  int row0 = wr0 + m, row1 = wr0 + 16 + m;
  int cr0 = row0 < N ? row0 : N-1;
  int cr1 = row1 < N ? row1 : N-1;
  const unsigned short* mrow0 = msgh   + (size_t)cr0*DD;
  const unsigned short* mrow1 = msgh   + (size_t)cr1*DD;
  const unsigned short* erow0 = ego_in + (size_t)cr0*fs;
  const unsigned short* erow1 = ego_in + (size_t)cr1*fs;
  const unsigned short* wrow  = wb + (size_t)m*K2;

  f32x4 acc[8][2];
#pragma unroll
  for (int ct = 0; ct < 8; ct++){ acc[ct][0] = (f32x4)0.f; acc[ct][1] = (f32x4)0.f; }

#pragma unroll
  for (int cc = 0; cc < 4; cc++){
    int c = cc*32 + q*8;
    short8 m0 = *(const short8*)(mrow0 + c);
    short8 m1 = *(const short8*)(mrow1 + c);
    short8 e0 = *(const short8*)(erow0 + c);
    short8 e1 = *(const short8*)(erow1 + c);
    short8 p0 = prod8(m0, e0);
    short8 p1 = prod8(m1, e1);
#pragma unroll
    for (int ct = 0; ct < 8; ct++){
      short8 bm = *(const short8*)(wrow + (size_t)ct*16*K2 + c);
      short8 bp = *(const short8*)(wrow + (size_t)ct*16*K2 + DD + c);
      acc[ct][0] = __builtin_amdgcn_mfma_f32_16x16x32_bf16(m0, bm, acc[ct][0], 0, 0, 0);
      acc[ct][1] = __builtin_amdgcn_mfma_f32_16x16x32_bf16(m1, bm, acc[ct][1], 0, 0, 0);
      acc[ct][0] = __builtin_amdgcn_mfma_f32_16x16x32_bf16(p0, bp, acc[ct][0], 0, 0, 0);
      acc[ct][1] = __builtin_amdgcn_mfma_f32_16x16x32_bf16(p1, bp, acc[ct][1], 0, 0, 0);
    }
  }

#pragma unroll
  for (int rt = 0; rt < 2; rt++){
#pragma unroll
    for (int reg = 0; reg < 4; reg++){
      int gr = wr0 + rt*16 + q*4 + reg;
      float rs = 0.f;
#pragma unroll
      for (int ct = 0; ct < 8; ct++){
        float x = acc[ct][rt][reg] + bias[ct];
        x = (x > 0.f) ? x : 0.2f*x;
        rs += x*x;
        if (gr < N) ego_out[(size_t)gr*fs + ct*16 + m] = f2bf(x);
      }
#pragma unroll
      for (int o = 1; o < 16; o <<= 1) rs += __shfl_xor(rs, o, 16);
      if (m == 0 && gr < N)
        nscale[(size_t)gr*3] = 1.0f / fmaxf(sqrtf(rs), 1e-12f);
    }
  }
}

// ---------------- score: single pass, interleaved 4-stage rows + interleaved scales --------
__global__ void score_all_kernel(const int* __restrict__ eli, int Q,
                                 const unsigned int* __restrict__ feat4u, int fsU,
                                 const float* __restrict__ nsall,  // [n][3]
                                 float* __restrict__ out){
  int wid = (int)(((size_t)blockIdx.x*blockDim.x + threadIdx.x) >> 6);
  int lane = threadIdx.x & 63;
  if (wid >= Q) return;
  int s = eli[wid];
  int d = eli[Q + wid];
  const unsigned int* sr = feat4u + (size_t)s*fsU + lane;
  const unsigned int* dr = feat4u + (size_t)d*fsU + lane;
  unsigned int a0 = sr[0],   b0 = dr[0];
  unsigned int a1 = sr[64],  b1 = dr[64];
  unsigned int a2 = sr[128], b2 = dr[128];
  unsigned int a3 = sr[192], b3 = dr[192];
  float p0 = bf2f((unsigned short)a0)*bf2f((unsigned short)b0)
           + bf2f((unsigned short)(a0>>16))*bf2f((unsigned short)(b0>>16));
  float p1 = bf2f((unsigned short)a1)*bf2f((unsigned short)b1)
           + bf2f((unsigned short)(a1>>16))*bf2f((unsigned short)(b1>>16));
  float p2 = bf2f((unsigned short)a2)*bf2f((unsigned short)b2)
           + bf2f((unsigned short)(a2>>16))*bf2f((unsigned short)(b2>>16));
  float p3 = bf2f((unsigned short)a3)*bf2f((unsigned short)b3)
           + bf2f((unsigned short)(a3>>16))*bf2f((unsigned short)(b3>>16));
  for (int o = 32; o > 0; o >>= 1){
    p0 += __shfl_xor(p0, o, 64);
    p1 += __shfl_xor(p1, o, 64);
    p2 += __shfl_xor(p2, o, 64);
    p3 += __shfl_xor(p3, o, 64);
  }
  if (lane == 0){
    const float* ss = nsall + (size_t)s*3;
    const float* ds = nsall + (size_t)d*3;
    float r = p0;
    r += p1 * ss[0] * ds[0];
    r += p2 * ss[1] * ds[1];
    r += p3 * ss[2] * ds[2];
    out[wid] = r;
  }
}

extern "C" void kernel_launch(void* const* d_in, const int* in_sizes, int n_in,
                              void* d_out, int out_size, void* d_ws, size_t ws_size,
                              hipStream_t stream){
  const int*   edge_index = (const int*)d_in[0];
  const int*   eli        = (const int*)d_in[1];
  const float* ew         = (const float*)d_in[2];
  const float* emb        = (const float*)d_in[3];
  const float* gcw        = (const float*)d_in[4];
  const float* gcb        = (const float*)d_in[5];
  const float* biw        = (const float*)d_in[6];
  const float* bib        = (const float*)d_in[7];
  const int E   = in_sizes[2];
  const int Q   = in_sizes[1] / 2;
  const int N   = in_sizes[3] / DD;
  const int LYR = in_sizes[4] / (DD*DD);
  float* out = (float*)d_out;

  const int FS  = (LYR + 1) * DD;   // interleaved per-node feature stride (512 for LYR=3)
  const int FSU = FS / 2;

  char* base = (char*)d_ws;
  size_t off = 0;
  auto carve = [&](size_t bytes)->char*{
    char* r = base + off;
    off = align256(off + bytes);
    return r;
  };

  unsigned short* feat4  = (unsigned short*) carve((size_t)N*FS*sizeof(unsigned short));
  // msgh (layer loop) aliases csre (setup phase A temp) -- disjoint lifetimes
  size_t msgB_ = (size_t)N*DD*sizeof(unsigned short);
  size_t csreB_ = (size_t)E*sizeof(int2);
  unsigned short* msgh   = (unsigned short*) carve(msgB_ > csreB_ ? msgB_ : csreB_);
  int2*           csre   = (int2*)msgh;
  unsigned short* wb     = (unsigned short*) carve((size_t)LYR*DD*K2*sizeof(unsigned short));
  float*          nsall  = (float*)          carve((size_t)3*N*sizeof(float));
  int2*           rp2    = (int2*)           carve((size_t)N*sizeof(int2));
  int*            bcnt   = (int*)            carve((size_t)(NBMAX+1)*sizeof(int));
  int*            gcur   = bcnt + NBMAX;     // zeroed together with bcnt
  int*            bbase  = (int*)            carve((size_t)NBMAX*sizeof(int));
  int*            bcur   = (int*)            carve((size_t)NBMAX*sizeof(int));
  int2*           csre2  = (int2*)           carve((size_t)E*sizeof(int2));
  (void)n_in; (void)out_size; (void)ws_size;

  const int NB = (N + 127)/128;

  // setup: hist -> bucket scan -> raw fill -> merged sort(+rp2) -> pack+cvt
  hipMemsetAsync(bcnt, 0, (size_t)(NBMAX+1)*sizeof(int), stream);
  bucket_hist_kernel<<<(E + 8191)/8192, 256, 0, stream>>>(edge_index, E, bcnt, NB);
  bucket_scan_kernel<<<1, 1024, 0, stream>>>(bcnt, bbase, bcur, NB);
  fill_binned_kernel<<<(E + 4095)/4096, 256, 0, stream>>>(edge_index, ew, E, bcur, csre, NB);
  sortbkt2_kernel<<<NB, 256, 0, stream>>>(bbase, bcur, csre, csre2, rp2, gcur, N);
  {
    int total = LYR*DD*K2 + N*DD/2;
    pack_cvt_kernel<<<(total + 255)/256, 256, 0, stream>>>(
        gcw, biw, wb, LYR, emb, (unsigned int*)feat4, N*DD/2, FSU);
  }

  for (int l = 0; l < LYR; l++){
    int blocks = (int)(((size_t)N*64 + 255)/256);
    gather_kernel<<<blocks, 256, 0, stream>>>(rp2, csre2, feat4 + (size_t)l*DD, FS,
                                              (unsigned int*)msgh, N);
    transform_mfma_kernel<<<(N + 127)/128, 256, 0, stream>>>(
        feat4 + (size_t)l*DD, msgh, FS, wb + (size_t)l*DD*K2,
        gcb + (size_t)l*DD, bib + (size_t)l*DD,
        feat4 + (size_t)(l+1)*DD, nsall + l, N);
  }
  {
    int blocks = (int)(((size_t)Q*64 + 255)/256);
    score_all_kernel<<<blocks, 256, 0, stream>>>(eli, Q, (const unsigned int*)feat4, FSU,
                                                 nsall, out);
  }
}